// Round 1
// baseline (1222.767 us; speedup 1.0000x reference)
//
#include <hip/hip_runtime.h>

#define N_NODES 5000
#define NH 8

static __device__ __forceinline__ float selu_f(float x) {
    const float sc = 1.0507009873554805f;
    const float al = 1.6732632423543772f;
    return x > 0.f ? sc * x : sc * al * (__expf(x) - 1.f);
}

// ---------------- CSR build ----------------
__global__ void k_count(const int* __restrict__ ei, int* cnt, int E, int Esz) {
    int e = blockIdx.x * 256 + threadIdx.x;
    if (e >= Esz) return;
    int dst = (e < E) ? ei[E + e] : (e - E);
    atomicAdd(&cnt[dst], 1);
}

__global__ void k_scan(const int* __restrict__ cnt, int* __restrict__ rowp, int n) {
    __shared__ int buf[1024];
    __shared__ int carry;
    int t = threadIdx.x;
    if (t == 0) { carry = 0; rowp[0] = 0; }
    __syncthreads();
    for (int base = 0; base < n; base += 1024) {
        int v = (base + t < n) ? cnt[base + t] : 0;
        buf[t] = v;
        __syncthreads();
        for (int off = 1; off < 1024; off <<= 1) {
            int x = (t >= off) ? buf[t - off] : 0;
            __syncthreads();
            buf[t] += x;
            __syncthreads();
        }
        if (base + t < n) rowp[base + t + 1] = carry + buf[t];
        __syncthreads();
        if (t == 0) carry += buf[1023];
        __syncthreads();
    }
}

__global__ void k_fill(const int* __restrict__ ei, const int* __restrict__ rowp,
                       int* cur, int* ssrc, int E, int Esz) {
    int e = blockIdx.x * 256 + threadIdx.x;
    if (e >= Esz) return;
    int src, dst;
    if (e < E) { src = ei[e]; dst = ei[E + e]; }
    else       { src = e - E; dst = src; }
    int pos = rowp[dst] + atomicAdd(&cur[dst], 1);
    ssrc[pos] = src;
}

// ---------------- feat0 = selu(data @ W0 + b0), and c0 = data[:, :2] ----------------
__global__ void k_feat0(const float* __restrict__ data, const float* __restrict__ W0,
                        const float* __restrict__ b0, float* __restrict__ f0,
                        float* __restrict__ c0) {
    int n = blockIdx.x;
    int t = threadIdx.x;   // 256
    __shared__ float d[10];
    if (t < 10) d[t] = data[n * 10 + t];
    __syncthreads();
    float acc = b0[t];
    #pragma unroll
    for (int k = 0; k < 10; ++k) acc += d[k] * W0[k * 256 + t];
    f0[(size_t)n * 256 + t] = selu_f(acc);
    if (t < 2) c0[n * 2 + t] = d[t];
}

// ---------------- assemble af = [p0, p1, ..., feat] ----------------
__global__ void k_assemble(float* __restrict__ af,
                           const float* p0, const float* p1, const float* p2, const float* p3,
                           int np, const float* __restrict__ feat, int FC, int K) {
    int n = blockIdx.x, t = threadIdx.x;
    float* row = af + (size_t)n * K;
    for (int c = t; c < K; c += 256) {
        float v;
        if (c < 2 * np) {
            const float* p = (c < 2) ? p0 : (c < 4) ? p1 : (c < 6) ? p2 : p3;
            v = p[n * 2 + (c & 1)];
        } else {
            v = feat[(size_t)n * FC + (c - 2 * np)];
        }
        row[c] = v;
    }
}

// ---------------- fold attention vectors into W: folded[k,h] = sum_c W[k, h*C+c]*a[h,c] ----------------
__global__ void k_fold(const float* __restrict__ W, const float* __restrict__ a_s,
                       const float* __restrict__ a_d, float* fs, float* fd, int K, int C) {
    int idx = blockIdx.x * 256 + threadIdx.x;
    if (idx >= K * 8) return;
    int kk = idx >> 3, h = idx & 7;
    const float* wr = W + (size_t)kk * 8 * C + (size_t)h * C;
    const float* as = a_s + (size_t)h * C;
    const float* ad = a_d + (size_t)h * C;
    float s = 0.f, d = 0.f;
    for (int c = 0; c < C; ++c) { float w = wr[c]; s += w * as[c]; d += w * ad[c]; }
    fs[idx] = s; fd[idx] = d;
}

// ---------------- e_s/e_d = af @ folded ----------------
__global__ void k_e(const float* __restrict__ af, const float* __restrict__ fs,
                    const float* __restrict__ fd, float* es, float* ed, int K) {
    int idx = blockIdx.x * 256 + threadIdx.x;
    if (idx >= N_NODES * 8) return;
    int n = idx >> 3, h = idx & 7;
    const float* ar = af + (size_t)n * K;
    float s = 0.f, d = 0.f;
    for (int k = 0; k < K; ++k) { float a = ar[k]; s += a * fs[k * 8 + h]; d += a * fd[k * 8 + h]; }
    es[idx] = s; ed[idx] = d;
}

// ---------------- tiled fp32 GEMM: C[M,NC] = A[M,K] @ B[K,NC] ----------------
__global__ __launch_bounds__(256) void k_gemm(const float* __restrict__ A,
                                              const float* __restrict__ B,
                                              float* __restrict__ C, int M, int K, int NC) {
    __shared__ float As[16][68];
    __shared__ float Bs[16][64];
    int bm = blockIdx.y * 64, bn = blockIdx.x * 64;
    int tid = threadIdx.x;
    int tm = (tid >> 4) << 2;
    int tn = (tid & 15) << 2;
    float acc[4][4] = {};
    for (int k0 = 0; k0 < K; k0 += 16) {
        #pragma unroll
        for (int i = tid; i < 1024; i += 256) {
            int r = i >> 4, c = i & 15;
            int gm = bm + r, gk = k0 + c;
            As[c][r] = (gm < M && gk < K) ? A[(size_t)gm * K + gk] : 0.f;
        }
        #pragma unroll
        for (int i = tid; i < 1024; i += 256) {
            int r = i >> 6, c = i & 63;
            int gk = k0 + r, gn = bn + c;
            Bs[r][c] = (gk < K && gn < NC) ? B[(size_t)gk * NC + gn] : 0.f;
        }
        __syncthreads();
        #pragma unroll
        for (int kk = 0; kk < 16; ++kk) {
            float4 a4 = *reinterpret_cast<const float4*>(&As[kk][tm]);
            float4 b4 = *reinterpret_cast<const float4*>(&Bs[kk][tn]);
            float a[4] = {a4.x, a4.y, a4.z, a4.w};
            float b[4] = {b4.x, b4.y, b4.z, b4.w};
            #pragma unroll
            for (int i = 0; i < 4; ++i)
                #pragma unroll
                for (int j = 0; j < 4; ++j) acc[i][j] += a[i] * b[j];
        }
        __syncthreads();
    }
    #pragma unroll
    for (int i = 0; i < 4; ++i) {
        int gm = bm + tm + i;
        if (gm >= M) break;
        #pragma unroll
        for (int j = 0; j < 4; ++j) {
            int gn = bn + tn + j;
            if (gn < NC) C[(size_t)gm * NC + gn] = acc[i][j];
        }
    }
}

// ---------------- per-node softmax over incoming edges (wave per node) ----------------
__global__ void k_alpha(const float* __restrict__ es, const float* __restrict__ ed,
                        const int* __restrict__ rowp, const int* __restrict__ ssrc,
                        float* __restrict__ alpha, float* __restrict__ wsum) {
    int wid = (blockIdx.x * blockDim.x + threadIdx.x) >> 6;
    int lane = threadIdx.x & 63;
    if (wid >= N_NODES) return;
    int n = wid;
    int s0 = rowp[n], deg = rowp[n + 1] - s0;
    int h = lane & 7, ei = lane >> 3;
    float edh = ed[n * 8 + h];
    float m = -1e30f;
    for (int b = 0; b < deg; b += 8) {
        int e = b + ei;
        if (e < deg) {
            int src = ssrc[s0 + e];
            float x = es[src * 8 + h] + edh;
            x = x > 0.f ? x : 0.2f * x;
            m = fmaxf(m, x);
        }
    }
    m = fmaxf(m, __shfl_xor(m, 8));
    m = fmaxf(m, __shfl_xor(m, 16));
    m = fmaxf(m, __shfl_xor(m, 32));
    float ssum = 0.f;
    for (int b = 0; b < deg; b += 8) {
        int e = b + ei;
        if (e < deg) {
            int src = ssrc[s0 + e];
            float x = es[src * 8 + h] + edh;
            x = x > 0.f ? x : 0.2f * x;
            ssum += __expf(x - m);
        }
    }
    ssum += __shfl_xor(ssum, 8);
    ssum += __shfl_xor(ssum, 16);
    ssum += __shfl_xor(ssum, 32);
    float inv = 1.f / ssum;
    for (int b = 0; b < deg; b += 8) {
        int e = b + ei;
        if (e < deg) {
            int src = ssrc[s0 + e];
            float x = es[src * 8 + h] + edh;
            x = x > 0.f ? x : 0.2f * x;
            float a = __expf(x - m) * inv;
            alpha[(size_t)(s0 + e) * 8 + h] = a;
            float w = a;
            w += __shfl_xor(w, 1);
            w += __shfl_xor(w, 2);
            w += __shfl_xor(w, 4);
            if (h == 0) wsum[s0 + e] = w;
        }
    }
}

// ---------------- aggregation: feat_next = selu(mean_h sum_e alpha*h[src] + bias); coords update ----------------
template <int C>
__global__ void k_aggregate(const float* __restrict__ h, const float* __restrict__ alpha,
                            const float* __restrict__ wsum, const int* __restrict__ rowp,
                            const int* __restrict__ ssrc, const float* __restrict__ cprev,
                            const float* __restrict__ bias, float* __restrict__ fnext,
                            float* __restrict__ cnext) {
    int n = blockIdx.x, t = threadIdx.x;   // blockDim = min(C,256)
    int s0 = rowp[n], s1 = rowp[n + 1];
    float acc0 = 0.f, acc1 = 0.f, oc0 = 0.f, oc1 = 0.f;
    for (int s = s0; s < s1; ++s) {
        int src = ssrc[s];
        float a[8];
        #pragma unroll
        for (int hh = 0; hh < 8; ++hh) a[hh] = alpha[(size_t)s * 8 + hh];
        const float* hr = h + (size_t)src * 8 * C;
        float v0 = 0.f;
        #pragma unroll
        for (int hh = 0; hh < 8; ++hh) v0 += a[hh] * hr[hh * C + t];
        acc0 += v0;
        if (C == 512) {
            float v1 = 0.f;
            #pragma unroll
            for (int hh = 0; hh < 8; ++hh) v1 += a[hh] * hr[hh * C + t + 256];
            acc1 += v1;
        }
        float w = wsum[s];
        oc0 += w * cprev[src * 2];
        oc1 += w * cprev[src * 2 + 1];
    }
    fnext[(size_t)n * C + t] = selu_f(acc0 * 0.125f + bias[t]);
    if (C == 512) fnext[(size_t)n * C + t + 256] = selu_f(acc1 * 0.125f + bias[t + 256]);
    if (t == 0) {
        oc0 *= 0.2f * 0.125f;
        oc1 *= 0.2f * 0.125f;
        float a0 = cprev[n * 2], a1 = cprev[n * 2 + 1];
        cnext[n * 2]     = (a0 == 0.f) ? 0.f : ((a0 == 1.f) ? 1.f : oc0);
        cnext[n * 2 + 1] = (a1 == 1.f) ? 1.f : ((a1 == 0.f) ? 0.f : oc1);
    }
}

// ---------------- layer 4: coords only ----------------
__global__ void k_coords4(const float* __restrict__ wsum, const int* __restrict__ rowp,
                          const int* __restrict__ ssrc, const float* __restrict__ cprev,
                          float* __restrict__ outp) {
    int n = blockIdx.x * 256 + threadIdx.x;
    if (n >= N_NODES) return;
    int s0 = rowp[n], s1 = rowp[n + 1];
    float oc0 = 0.f, oc1 = 0.f;
    for (int s = s0; s < s1; ++s) {
        int src = ssrc[s];
        float w = wsum[s];
        oc0 += w * cprev[src * 2];
        oc1 += w * cprev[src * 2 + 1];
    }
    oc0 *= 0.2f * 0.125f;
    oc1 *= 0.2f * 0.125f;
    float a0 = cprev[n * 2], a1 = cprev[n * 2 + 1];
    outp[n * 2]     = (a0 == 0.f) ? 0.f : ((a0 == 1.f) ? 1.f : oc0);
    outp[n * 2 + 1] = (a1 == 1.f) ? 1.f : ((a1 == 0.f) ? 0.f : oc1);
}

extern "C" void kernel_launch(void* const* d_in, const int* in_sizes, int n_in,
                              void* d_out, int out_size, void* d_ws, size_t ws_size,
                              hipStream_t stream) {
    const float* data = (const float*)d_in[0];
    const int* ei = (const int*)d_in[1];
    const float* W0 = (const float*)d_in[2];
    const float* b0 = (const float*)d_in[3];
    int E = in_sizes[1] / 2;           // 40000
    int Esz = E + N_NODES;             // +self loops

    char* wp = (char*)d_ws;
    size_t off = 0;
    auto alloc = [&](size_t bytes) {
        void* p = wp + off;
        off += (bytes + 1023) & ~(size_t)1023;
        return p;
    };
    float* hbuf  = (float*)alloc((size_t)N_NODES * 4096 * 4);
    float* af    = (float*)alloc((size_t)N_NODES * 516 * 4);
    float* fA    = (float*)alloc((size_t)N_NODES * 512 * 4);
    float* fB    = (float*)alloc((size_t)N_NODES * 512 * 4);
    float* alpha = (float*)alloc((size_t)Esz * 8 * 4);
    float* wsum  = (float*)alloc((size_t)Esz * 4);
    float* es    = (float*)alloc((size_t)N_NODES * 8 * 4);
    float* ebd   = (float*)alloc((size_t)N_NODES * 8 * 4);
    float* fs    = (float*)alloc(516 * 8 * 4);
    float* fd    = (float*)alloc(516 * 8 * 4);
    float* c0    = (float*)alloc(N_NODES * 2 * 4);
    float* c1    = (float*)alloc(N_NODES * 2 * 4);
    float* c2    = (float*)alloc(N_NODES * 2 * 4);
    float* c3    = (float*)alloc(N_NODES * 2 * 4);
    int* cnt  = (int*)alloc(N_NODES * 4);
    int* rowp = (int*)alloc((N_NODES + 1) * 4);
    int* cur  = (int*)alloc(N_NODES * 4);
    int* ssrc = (int*)alloc(Esz * 4);

    hipMemsetAsync(cnt, 0, N_NODES * 4, stream);
    hipMemsetAsync(cur, 0, N_NODES * 4, stream);
    int gE = (Esz + 255) / 256;
    k_count<<<gE, 256, 0, stream>>>(ei, cnt, E, Esz);
    k_scan<<<1, 1024, 0, stream>>>(cnt, rowp, N_NODES);
    k_fill<<<gE, 256, 0, stream>>>(ei, rowp, cur, ssrc, E, Esz);
    k_feat0<<<N_NODES, 256, 0, stream>>>(data, W0, b0, fA, c0);

    struct LP { const float *W, *as, *ad, *bs; int K, C; };
    LP L[4] = {
        {(const float*)d_in[4],  (const float*)d_in[5],  (const float*)d_in[6],  (const float*)d_in[7],  258, 512},
        {(const float*)d_in[8],  (const float*)d_in[9],  (const float*)d_in[10], (const float*)d_in[11], 516, 256},
        {(const float*)d_in[12], (const float*)d_in[13], (const float*)d_in[14], (const float*)d_in[15], 262, 128},
        {(const float*)d_in[16], (const float*)d_in[17], (const float*)d_in[18], (const float*)d_in[19], 136, 20},
    };
    float* cbuf[4] = {c0, c1, c2, c3};
    float* featin[4] = {fA, fB, fA, fB};
    int FC[4] = {256, 512, 256, 128};

    for (int li = 0; li < 4; ++li) {
        LP& lp = L[li];
        const float* p[4] = {nullptr, nullptr, nullptr, nullptr};
        for (int j = 0; j <= li; ++j) p[j] = cbuf[li - j];
        k_assemble<<<N_NODES, 256, 0, stream>>>(af, p[0], p[1], p[2], p[3], li + 1,
                                                featin[li], FC[li], lp.K);
        k_fold<<<(lp.K * 8 + 255) / 256, 256, 0, stream>>>(lp.W, lp.as, lp.ad, fs, fd, lp.K, lp.C);
        k_e<<<(N_NODES * 8 + 255) / 256, 256, 0, stream>>>(af, fs, fd, es, ebd, lp.K);
        if (li < 3) {
            dim3 gg((lp.C * 8) / 64, (N_NODES + 63) / 64);
            k_gemm<<<gg, 256, 0, stream>>>(af, lp.W, hbuf, N_NODES, lp.K, lp.C * 8);
        }
        k_alpha<<<(N_NODES + 3) / 4, 256, 0, stream>>>(es, ebd, rowp, ssrc, alpha, wsum);
        if (li == 0)
            k_aggregate<512><<<N_NODES, 256, 0, stream>>>(hbuf, alpha, wsum, rowp, ssrc,
                                                          cbuf[0], lp.bs, fB, cbuf[1]);
        else if (li == 1)
            k_aggregate<256><<<N_NODES, 256, 0, stream>>>(hbuf, alpha, wsum, rowp, ssrc,
                                                          cbuf[1], lp.bs, fA, cbuf[2]);
        else if (li == 2)
            k_aggregate<128><<<N_NODES, 128, 0, stream>>>(hbuf, alpha, wsum, rowp, ssrc,
                                                          cbuf[2], lp.bs, fB, cbuf[3]);
        else
            k_coords4<<<(N_NODES + 255) / 256, 256, 0, stream>>>(wsum, rowp, ssrc, cbuf[3],
                                                                 (float*)d_out);
    }
}

// Round 2
// 532.472 us; speedup vs baseline: 2.2964x; 2.2964x over previous
//
#include <hip/hip_runtime.h>

#define N_NODES 5000
#define NH 8

typedef unsigned short u16;
typedef short bf16x8 __attribute__((ext_vector_type(8)));
typedef float f32x4 __attribute__((ext_vector_type(4)));

static __device__ __forceinline__ float selu_f(float x) {
    const float sc = 1.0507009873554805f;
    const float al = 1.6732632423543772f;
    return x > 0.f ? sc * x : sc * al * (__expf(x) - 1.f);
}

static __device__ __forceinline__ u16 f2bf(float x) {
    union { float f; unsigned u; } v; v.f = x;
    unsigned r = v.u + 0x7fff + ((v.u >> 16) & 1);
    return (u16)(r >> 16);
}

// ---------------- CSR build ----------------
__global__ void k_count(const int* __restrict__ ei, int* cnt, int E, int Esz) {
    int e = blockIdx.x * 256 + threadIdx.x;
    if (e >= Esz) return;
    int dst = (e < E) ? ei[E + e] : (e - E);
    atomicAdd(&cnt[dst], 1);
}

__global__ void k_scan(const int* __restrict__ cnt, int* __restrict__ rowp, int n) {
    __shared__ int buf[1024];
    __shared__ int carry;
    int t = threadIdx.x;
    if (t == 0) { carry = 0; rowp[0] = 0; }
    __syncthreads();
    for (int base = 0; base < n; base += 1024) {
        int v = (base + t < n) ? cnt[base + t] : 0;
        buf[t] = v;
        __syncthreads();
        for (int off = 1; off < 1024; off <<= 1) {
            int x = (t >= off) ? buf[t - off] : 0;
            __syncthreads();
            buf[t] += x;
            __syncthreads();
        }
        if (base + t < n) rowp[base + t + 1] = carry + buf[t];
        __syncthreads();
        if (t == 0) carry += buf[1023];
        __syncthreads();
    }
}

__global__ void k_fill(const int* __restrict__ ei, const int* __restrict__ rowp,
                       int* cur, int* ssrc, int E, int Esz) {
    int e = blockIdx.x * 256 + threadIdx.x;
    if (e >= Esz) return;
    int src, dst;
    if (e < E) { src = ei[e]; dst = ei[E + e]; }
    else       { src = e - E; dst = src; }
    int pos = rowp[dst] + atomicAdd(&cur[dst], 1);
    ssrc[pos] = src;
}

// ---------------- feat0 = selu(data @ W0 + b0), and c0 = data[:, :2] ----------------
__global__ void k_feat0(const float* __restrict__ data, const float* __restrict__ W0,
                        const float* __restrict__ b0, float* __restrict__ f0,
                        float* __restrict__ c0) {
    int n = blockIdx.x;
    int t = threadIdx.x;   // 256
    __shared__ float d[10];
    if (t < 10) d[t] = data[n * 10 + t];
    __syncthreads();
    float acc = b0[t];
    #pragma unroll
    for (int k = 0; k < 10; ++k) acc += d[k] * W0[k * 256 + t];
    f0[(size_t)n * 256 + t] = selu_f(acc);
    if (t < 2) c0[n * 2 + t] = d[t];
}

// ---------------- assemble af = [p0, p1, ..., feat] ----------------
__global__ void k_assemble(float* __restrict__ af,
                           const float* p0, const float* p1, const float* p2, const float* p3,
                           int np, const float* __restrict__ feat, int FC, int K) {
    int n = blockIdx.x, t = threadIdx.x;
    float* row = af + (size_t)n * K;
    for (int c = t; c < K; c += 256) {
        float v;
        if (c < 2 * np) {
            const float* p = (c < 2) ? p0 : (c < 4) ? p1 : (c < 6) ? p2 : p3;
            v = p[n * 2 + (c & 1)];
        } else {
            v = feat[(size_t)n * FC + (c - 2 * np)];
        }
        row[c] = v;
    }
}

// ---------------- fold: folded[k,h] = sum_c W[k, h*C+c]*a[h,c]  (wave per k) ----------------
__global__ void k_fold2(const float* __restrict__ W, const float* __restrict__ a_s,
                        const float* __restrict__ a_d, float* __restrict__ fs,
                        float* __restrict__ fd, int K, int C) {
    int k = blockIdx.x;
    int lane = threadIdx.x;   // 64
    float s[8] = {0.f,0.f,0.f,0.f,0.f,0.f,0.f,0.f};
    float d[8] = {0.f,0.f,0.f,0.f,0.f,0.f,0.f,0.f};
    const float* wr = W + (size_t)k * 8 * C;
    for (int c = lane; c < C; c += 64) {
        #pragma unroll
        for (int h = 0; h < 8; ++h) {
            float w = wr[h * C + c];
            s[h] += w * a_s[h * C + c];
            d[h] += w * a_d[h * C + c];
        }
    }
    #pragma unroll
    for (int off = 32; off >= 1; off >>= 1) {
        #pragma unroll
        for (int h = 0; h < 8; ++h) {
            s[h] += __shfl_xor(s[h], off);
            d[h] += __shfl_xor(d[h], off);
        }
    }
    if (lane == 0) {
        #pragma unroll
        for (int h = 0; h < 8; ++h) { fs[k * 8 + h] = s[h]; fd[k * 8 + h] = d[h]; }
    }
}

// ---------------- e_s/e_d = af @ [fs|fd]  (block per 16 nodes, LDS tiled) ----------------
__global__ __launch_bounds__(256) void k_e2(const float* __restrict__ af,
                                            const float* __restrict__ fs,
                                            const float* __restrict__ fd,
                                            float* __restrict__ es, float* __restrict__ ed,
                                            int K) {
    __shared__ float As[16][65];
    __shared__ float Fs[64][16];
    int tid = threadIdx.x;
    int n0 = blockIdx.x * 16;
    int i = tid >> 4, j = tid & 15;
    float acc = 0.f;
    for (int k0 = 0; k0 < K; k0 += 64) {
        for (int idx = tid; idx < 1024; idx += 256) {
            int r = idx >> 6, cc = idx & 63;
            int gk = k0 + cc, gn = n0 + r;
            As[r][cc] = (gk < K && gn < N_NODES) ? af[(size_t)gn * K + gk] : 0.f;
        }
        for (int idx = tid; idx < 1024; idx += 256) {
            int cc = idx >> 4, jj = idx & 15;
            int gk = k0 + cc;
            float v = 0.f;
            if (gk < K) v = (jj < 8) ? fs[gk * 8 + jj] : fd[gk * 8 + (jj - 8)];
            Fs[cc][jj] = v;
        }
        __syncthreads();
        #pragma unroll 8
        for (int cc = 0; cc < 64; ++cc) acc += As[i][cc] * Fs[cc][j];
        __syncthreads();
    }
    int n = n0 + i;
    if (n < N_NODES) {
        if (j < 8) es[n * 8 + j] = acc;
        else       ed[n * 8 + (j - 8)] = acc;
    }
}

// ---------------- fp32 -> bf16 conversions ----------------
__global__ void k_abf16(const float* __restrict__ af, u16* __restrict__ afb, int K, int Kp) {
    int n = blockIdx.y;
    for (int k = threadIdx.x; k < Kp; k += 256)
        afb[(size_t)n * Kp + k] = (k < K) ? f2bf(af[(size_t)n * K + k]) : (u16)0;
}

// W [K][NC] fp32 -> Wt [NC][Kp] bf16 (transposed, k-padded)
__global__ __launch_bounds__(256) void k_wtr(const float* __restrict__ W, u16* __restrict__ Wt,
                                             int K, int Kp, int NC) {
    __shared__ float tile[32][33];
    int bx = blockIdx.x, by = blockIdx.y;
    int tid = threadIdx.x;
    for (int idx = tid; idx < 1024; idx += 256) {
        int kr = idx >> 5, nc = idx & 31;
        int gk = by * 32 + kr, gn = bx * 32 + nc;
        tile[kr][nc] = (gk < K) ? W[(size_t)gk * NC + gn] : 0.f;
    }
    __syncthreads();
    for (int idx = tid; idx < 1024; idx += 256) {
        int nr = idx >> 5, kc = idx & 31;
        int gn = bx * 32 + nr, gk = by * 32 + kc;
        Wt[(size_t)gn * Kp + gk] = f2bf(tile[kc][nr]);
    }
}

// ---------------- bf16 MFMA GEMM: C[M,NC] = A[M,Kp] @ Bt[NC,Kp]^T ----------------
__global__ __launch_bounds__(256) void k_gemm_mfma(const u16* __restrict__ Ab,
                                                   const u16* __restrict__ Bt,
                                                   float* __restrict__ C,
                                                   int M, int Kp, int NC) {
    __shared__ u16 As[128 * 32];
    __shared__ u16 Bs[128 * 32];
    int tid = threadIdx.x;
    int wave = tid >> 6, lane = tid & 63;
    int bm = blockIdx.y * 128, bn = blockIdx.x * 128;
    int wm = (wave >> 1) * 64, wn = (wave & 1) * 64;
    int l16 = lane & 15, q = lane >> 4;
    f32x4 acc[4][4] = {};
    for (int k0 = 0; k0 < Kp; k0 += 32) {
        #pragma unroll
        for (int it = 0; it < 2; ++it) {
            int seg = tid + it * 256;
            int row = seg >> 2, sq = seg & 3;
            uint4 va = {0u, 0u, 0u, 0u};
            int grow = bm + row;
            if (grow < M) va = *(const uint4*)(Ab + (size_t)grow * Kp + k0 + sq * 8);
            *(uint4*)(As + row * 32 + ((sq ^ (row & 3)) * 8)) = va;
            uint4 vb = *(const uint4*)(Bt + (size_t)(bn + row) * Kp + k0 + sq * 8);
            *(uint4*)(Bs + row * 32 + ((sq ^ (row & 3)) * 8)) = vb;
        }
        __syncthreads();
        bf16x8 fa[4], fb[4];
        #pragma unroll
        for (int mi = 0; mi < 4; ++mi) {
            int row = wm + mi * 16 + l16;
            fa[mi] = *(const bf16x8*)(As + row * 32 + ((q ^ (row & 3)) * 8));
            int col = wn + mi * 16 + l16;
            fb[mi] = *(const bf16x8*)(Bs + col * 32 + ((q ^ (col & 3)) * 8));
        }
        #pragma unroll
        for (int mi = 0; mi < 4; ++mi)
            #pragma unroll
            for (int ni = 0; ni < 4; ++ni)
                acc[mi][ni] = __builtin_amdgcn_mfma_f32_16x16x32_bf16(fa[mi], fb[ni], acc[mi][ni], 0, 0, 0);
        __syncthreads();
    }
    #pragma unroll
    for (int mi = 0; mi < 4; ++mi) {
        int row0 = bm + wm + mi * 16 + q * 4;
        #pragma unroll
        for (int ni = 0; ni < 4; ++ni) {
            int col = bn + wn + ni * 16 + l16;
            #pragma unroll
            for (int r = 0; r < 4; ++r) {
                int row = row0 + r;
                if (row < M) C[(size_t)row * NC + col] = acc[mi][ni][r];
            }
        }
    }
}

// ---------------- per-node softmax over incoming edges (wave per node) ----------------
__global__ void k_alpha(const float* __restrict__ es, const float* __restrict__ ed,
                        const int* __restrict__ rowp, const int* __restrict__ ssrc,
                        float* __restrict__ alpha, float* __restrict__ wsum) {
    int wid = (blockIdx.x * blockDim.x + threadIdx.x) >> 6;
    int lane = threadIdx.x & 63;
    if (wid >= N_NODES) return;
    int n = wid;
    int s0 = rowp[n], deg = rowp[n + 1] - s0;
    int h = lane & 7, ei = lane >> 3;
    float edh = ed[n * 8 + h];
    float m = -1e30f;
    for (int b = 0; b < deg; b += 8) {
        int e = b + ei;
        if (e < deg) {
            int src = ssrc[s0 + e];
            float x = es[src * 8 + h] + edh;
            x = x > 0.f ? x : 0.2f * x;
            m = fmaxf(m, x);
        }
    }
    m = fmaxf(m, __shfl_xor(m, 8));
    m = fmaxf(m, __shfl_xor(m, 16));
    m = fmaxf(m, __shfl_xor(m, 32));
    float ssum = 0.f;
    for (int b = 0; b < deg; b += 8) {
        int e = b + ei;
        if (e < deg) {
            int src = ssrc[s0 + e];
            float x = es[src * 8 + h] + edh;
            x = x > 0.f ? x : 0.2f * x;
            ssum += __expf(x - m);
        }
    }
    ssum += __shfl_xor(ssum, 8);
    ssum += __shfl_xor(ssum, 16);
    ssum += __shfl_xor(ssum, 32);
    float inv = 1.f / ssum;
    for (int b = 0; b < deg; b += 8) {
        int e = b + ei;
        if (e < deg) {
            int src = ssrc[s0 + e];
            float x = es[src * 8 + h] + edh;
            x = x > 0.f ? x : 0.2f * x;
            float a = __expf(x - m) * inv;
            alpha[(size_t)(s0 + e) * 8 + h] = a;
            float w = a;
            w += __shfl_xor(w, 1);
            w += __shfl_xor(w, 2);
            w += __shfl_xor(w, 4);
            if (h == 0) wsum[s0 + e] = w;
        }
    }
}

// ---------------- aggregation ----------------
template <int C>
__global__ void k_aggregate(const float* __restrict__ h, const float* __restrict__ alpha,
                            const float* __restrict__ wsum, const int* __restrict__ rowp,
                            const int* __restrict__ ssrc, const float* __restrict__ cprev,
                            const float* __restrict__ bias, float* __restrict__ fnext,
                            float* __restrict__ cnext) {
    int n = blockIdx.x, t = threadIdx.x;
    int s0 = rowp[n], s1 = rowp[n + 1];
    float acc0 = 0.f, acc1 = 0.f, oc0 = 0.f, oc1 = 0.f;
    for (int s = s0; s < s1; ++s) {
        int src = ssrc[s];
        float a[8];
        #pragma unroll
        for (int hh = 0; hh < 8; ++hh) a[hh] = alpha[(size_t)s * 8 + hh];
        const float* hr = h + (size_t)src * 8 * C;
        float v0 = 0.f;
        #pragma unroll
        for (int hh = 0; hh < 8; ++hh) v0 += a[hh] * hr[hh * C + t];
        acc0 += v0;
        if (C == 512) {
            float v1 = 0.f;
            #pragma unroll
            for (int hh = 0; hh < 8; ++hh) v1 += a[hh] * hr[hh * C + t + 256];
            acc1 += v1;
        }
        float w = wsum[s];
        oc0 += w * cprev[src * 2];
        oc1 += w * cprev[src * 2 + 1];
    }
    fnext[(size_t)n * C + t] = selu_f(acc0 * 0.125f + bias[t]);
    if (C == 512) fnext[(size_t)n * C + t + 256] = selu_f(acc1 * 0.125f + bias[t + 256]);
    if (t == 0) {
        oc0 *= 0.2f * 0.125f;
        oc1 *= 0.2f * 0.125f;
        float a0 = cprev[n * 2], a1 = cprev[n * 2 + 1];
        cnext[n * 2]     = (a0 == 0.f) ? 0.f : ((a0 == 1.f) ? 1.f : oc0);
        cnext[n * 2 + 1] = (a1 == 1.f) ? 1.f : ((a1 == 0.f) ? 0.f : oc1);
    }
}

// ---------------- layer 4: coords only ----------------
__global__ void k_coords4(const float* __restrict__ wsum, const int* __restrict__ rowp,
                          const int* __restrict__ ssrc, const float* __restrict__ cprev,
                          float* __restrict__ outp) {
    int n = blockIdx.x * 256 + threadIdx.x;
    if (n >= N_NODES) return;
    int s0 = rowp[n], s1 = rowp[n + 1];
    float oc0 = 0.f, oc1 = 0.f;
    for (int s = s0; s < s1; ++s) {
        int src = ssrc[s];
        float w = wsum[s];
        oc0 += w * cprev[src * 2];
        oc1 += w * cprev[src * 2 + 1];
    }
    oc0 *= 0.2f * 0.125f;
    oc1 *= 0.2f * 0.125f;
    float a0 = cprev[n * 2], a1 = cprev[n * 2 + 1];
    outp[n * 2]     = (a0 == 0.f) ? 0.f : ((a0 == 1.f) ? 1.f : oc0);
    outp[n * 2 + 1] = (a1 == 1.f) ? 1.f : ((a1 == 0.f) ? 0.f : oc1);
}

extern "C" void kernel_launch(void* const* d_in, const int* in_sizes, int n_in,
                              void* d_out, int out_size, void* d_ws, size_t ws_size,
                              hipStream_t stream) {
    const float* data = (const float*)d_in[0];
    const int* ei = (const int*)d_in[1];
    const float* W0 = (const float*)d_in[2];
    const float* b0 = (const float*)d_in[3];
    int E = in_sizes[1] / 2;           // 40000
    int Esz = E + N_NODES;             // +self loops

    char* wp = (char*)d_ws;
    size_t off = 0;
    auto alloc = [&](size_t bytes) {
        void* p = wp + off;
        off += (bytes + 1023) & ~(size_t)1023;
        return p;
    };
    float* hbuf  = (float*)alloc((size_t)N_NODES * 4096 * 4);
    float* af    = (float*)alloc((size_t)N_NODES * 516 * 4);
    float* fA    = (float*)alloc((size_t)N_NODES * 512 * 4);
    float* fB    = (float*)alloc((size_t)N_NODES * 512 * 4);
    u16*   afb   = (u16*)alloc((size_t)N_NODES * 544 * 2);
    u16*   Wtb   = (u16*)alloc((size_t)4096 * 544 * 2);
    float* alpha = (float*)alloc((size_t)Esz * 8 * 4);
    float* wsum  = (float*)alloc((size_t)Esz * 4);
    float* es    = (float*)alloc((size_t)N_NODES * 8 * 4);
    float* ebd   = (float*)alloc((size_t)N_NODES * 8 * 4);
    float* fs    = (float*)alloc(516 * 8 * 4);
    float* fd    = (float*)alloc(516 * 8 * 4);
    float* c0    = (float*)alloc(N_NODES * 2 * 4);
    float* c1    = (float*)alloc(N_NODES * 2 * 4);
    float* c2    = (float*)alloc(N_NODES * 2 * 4);
    float* c3    = (float*)alloc(N_NODES * 2 * 4);
    int* cnt  = (int*)alloc(N_NODES * 4);
    int* rowp = (int*)alloc((N_NODES + 1) * 4);
    int* cur  = (int*)alloc(N_NODES * 4);
    int* ssrc = (int*)alloc(Esz * 4);

    hipMemsetAsync(cnt, 0, N_NODES * 4, stream);
    hipMemsetAsync(cur, 0, N_NODES * 4, stream);
    int gE = (Esz + 255) / 256;
    k_count<<<gE, 256, 0, stream>>>(ei, cnt, E, Esz);
    k_scan<<<1, 1024, 0, stream>>>(cnt, rowp, N_NODES);
    k_fill<<<gE, 256, 0, stream>>>(ei, rowp, cur, ssrc, E, Esz);
    k_feat0<<<N_NODES, 256, 0, stream>>>(data, W0, b0, fA, c0);

    struct LP { const float *W, *as, *ad, *bs; int K, C; };
    LP L[4] = {
        {(const float*)d_in[4],  (const float*)d_in[5],  (const float*)d_in[6],  (const float*)d_in[7],  258, 512},
        {(const float*)d_in[8],  (const float*)d_in[9],  (const float*)d_in[10], (const float*)d_in[11], 516, 256},
        {(const float*)d_in[12], (const float*)d_in[13], (const float*)d_in[14], (const float*)d_in[15], 262, 128},
        {(const float*)d_in[16], (const float*)d_in[17], (const float*)d_in[18], (const float*)d_in[19], 136, 20},
    };
    float* cbuf[4] = {c0, c1, c2, c3};
    float* featin[4] = {fA, fB, fA, fB};
    int FC[4] = {256, 512, 256, 128};

    for (int li = 0; li < 4; ++li) {
        LP& lp = L[li];
        const float* p[4] = {nullptr, nullptr, nullptr, nullptr};
        for (int j = 0; j <= li; ++j) p[j] = cbuf[li - j];
        k_assemble<<<N_NODES, 256, 0, stream>>>(af, p[0], p[1], p[2], p[3], li + 1,
                                                featin[li], FC[li], lp.K);
        k_fold2<<<lp.K, 64, 0, stream>>>(lp.W, lp.as, lp.ad, fs, fd, lp.K, lp.C);
        k_e2<<<(N_NODES + 15) / 16, 256, 0, stream>>>(af, fs, fd, es, ebd, lp.K);
        if (li < 3) {
            int NCc = lp.C * 8;
            int Kp = ((lp.K + 31) / 32) * 32;
            k_abf16<<<dim3(1, N_NODES), 256, 0, stream>>>(af, afb, lp.K, Kp);
            k_wtr<<<dim3(NCc / 32, Kp / 32), 256, 0, stream>>>(lp.W, Wtb, lp.K, Kp, NCc);
            k_gemm_mfma<<<dim3(NCc / 128, (N_NODES + 127) / 128), 256, 0, stream>>>(
                afb, Wtb, hbuf, N_NODES, Kp, NCc);
        }
        k_alpha<<<(N_NODES + 3) / 4, 256, 0, stream>>>(es, ebd, rowp, ssrc, alpha, wsum);
        if (li == 0)
            k_aggregate<512><<<N_NODES, 256, 0, stream>>>(hbuf, alpha, wsum, rowp, ssrc,
                                                          cbuf[0], lp.bs, fB, cbuf[1]);
        else if (li == 1)
            k_aggregate<256><<<N_NODES, 256, 0, stream>>>(hbuf, alpha, wsum, rowp, ssrc,
                                                          cbuf[1], lp.bs, fA, cbuf[2]);
        else if (li == 2)
            k_aggregate<128><<<N_NODES, 128, 0, stream>>>(hbuf, alpha, wsum, rowp, ssrc,
                                                          cbuf[2], lp.bs, fB, cbuf[3]);
        else
            k_coords4<<<(N_NODES + 255) / 256, 256, 0, stream>>>(wsum, rowp, ssrc, cbuf[3],
                                                                 (float*)d_out);
    }
}

// Round 3
// 430.517 us; speedup vs baseline: 2.8402x; 1.2368x over previous
//
#include <hip/hip_runtime.h>

#define N_NODES 5000
#define NH 8

typedef unsigned short u16;
typedef short bf16x8 __attribute__((ext_vector_type(8)));
typedef float f32x4 __attribute__((ext_vector_type(4)));

static __device__ __forceinline__ float selu_f(float x) {
    const float sc = 1.0507009873554805f;
    const float al = 1.6732632423543772f;
    return x > 0.f ? sc * x : sc * al * (__expf(x) - 1.f);
}

static __device__ __forceinline__ u16 f2bf(float x) {
    union { float f; unsigned u; } v; v.f = x;
    unsigned r = v.u + 0x7fff + ((v.u >> 16) & 1);
    return (u16)(r >> 16);
}

static __device__ __forceinline__ float bf2f(unsigned hi16) {
    union { unsigned u; float f; } v; v.u = hi16 << 16;
    return v.f;
}

// ---------------- CSR build ----------------
__global__ void k_count(const int* __restrict__ ei, int* cnt, int E, int Esz) {
    int e = blockIdx.x * 256 + threadIdx.x;
    if (e >= Esz) return;
    int dst = (e < E) ? ei[E + e] : (e - E);
    atomicAdd(&cnt[dst], 1);
}

__global__ void k_scan(const int* __restrict__ cnt, int* __restrict__ rowp, int n) {
    __shared__ int buf[1024];
    __shared__ int carry;
    int t = threadIdx.x;
    if (t == 0) { carry = 0; rowp[0] = 0; }
    __syncthreads();
    for (int base = 0; base < n; base += 1024) {
        int v = (base + t < n) ? cnt[base + t] : 0;
        buf[t] = v;
        __syncthreads();
        for (int off = 1; off < 1024; off <<= 1) {
            int x = (t >= off) ? buf[t - off] : 0;
            __syncthreads();
            buf[t] += x;
            __syncthreads();
        }
        if (base + t < n) rowp[base + t + 1] = carry + buf[t];
        __syncthreads();
        if (t == 0) carry += buf[1023];
        __syncthreads();
    }
}

__global__ void k_fill(const int* __restrict__ ei, const int* __restrict__ rowp,
                       int* cur, int* ssrc, int E, int Esz) {
    int e = blockIdx.x * 256 + threadIdx.x;
    if (e >= Esz) return;
    int src, dst;
    if (e < E) { src = ei[e]; dst = ei[E + e]; }
    else       { src = e - E; dst = src; }
    int pos = rowp[dst] + atomicAdd(&cur[dst], 1);
    ssrc[pos] = src;
}

// ---------------- feat0 = selu(data @ W0 + b0), and c0 = data[:, :2] ----------------
__global__ void k_feat0(const float* __restrict__ data, const float* __restrict__ W0,
                        const float* __restrict__ b0, float* __restrict__ f0,
                        float* __restrict__ c0) {
    int n = blockIdx.x;
    int t = threadIdx.x;   // 256
    __shared__ float d[10];
    if (t < 10) d[t] = data[n * 10 + t];
    __syncthreads();
    float acc = b0[t];
    #pragma unroll
    for (int k = 0; k < 10; ++k) acc += d[k] * W0[k * 256 + t];
    f0[(size_t)n * 256 + t] = selu_f(acc);
    if (t < 2) c0[n * 2 + t] = d[t];
}

// ---------------- assemble af = [p0, p1, ..., feat] (fp32) + afb (bf16, k-padded) ----------------
__global__ void k_assemble(float* __restrict__ af, u16* __restrict__ afb,
                           const float* p0, const float* p1, const float* p2, const float* p3,
                           int np, const float* __restrict__ feat, int FC, int K, int Kp) {
    int n = blockIdx.x, t = threadIdx.x;
    float* row = af + (size_t)n * K;
    u16* rowb = afb + (size_t)n * Kp;
    for (int c = t; c < Kp; c += 256) {
        float v = 0.f;
        if (c < K) {
            if (c < 2 * np) {
                const float* p = (c < 2) ? p0 : (c < 4) ? p1 : (c < 6) ? p2 : p3;
                v = p[n * 2 + (c & 1)];
            } else {
                v = feat[(size_t)n * FC + (c - 2 * np)];
            }
            row[c] = v;
        }
        rowb[c] = f2bf(v);
    }
}

// ---------------- fold: folded[k,h] = sum_c W[k, h*C+c]*a[h,c]  (wave per k, fp32) ----------------
__global__ void k_fold2(const float* __restrict__ W, const float* __restrict__ a_s,
                        const float* __restrict__ a_d, float* __restrict__ fs,
                        float* __restrict__ fd, int K, int C) {
    int k = blockIdx.x;
    int lane = threadIdx.x;   // 64
    float s[8] = {0.f,0.f,0.f,0.f,0.f,0.f,0.f,0.f};
    float d[8] = {0.f,0.f,0.f,0.f,0.f,0.f,0.f,0.f};
    const float* wr = W + (size_t)k * 8 * C;
    for (int c = lane; c < C; c += 64) {
        #pragma unroll
        for (int h = 0; h < 8; ++h) {
            float w = wr[h * C + c];
            s[h] += w * a_s[h * C + c];
            d[h] += w * a_d[h * C + c];
        }
    }
    #pragma unroll
    for (int off = 32; off >= 1; off >>= 1) {
        #pragma unroll
        for (int h = 0; h < 8; ++h) {
            s[h] += __shfl_xor(s[h], off);
            d[h] += __shfl_xor(d[h], off);
        }
    }
    if (lane == 0) {
        #pragma unroll
        for (int h = 0; h < 8; ++h) { fs[k * 8 + h] = s[h]; fd[k * 8 + h] = d[h]; }
    }
}

// ---------------- e_s/e_d = af @ [fs|fd]  (block per 16 nodes, LDS tiled, fp32) ----------------
__global__ __launch_bounds__(256) void k_e2(const float* __restrict__ af,
                                            const float* __restrict__ fs,
                                            const float* __restrict__ fd,
                                            float* __restrict__ es, float* __restrict__ ed,
                                            int K) {
    __shared__ float As[16][65];
    __shared__ float Fs[64][16];
    int tid = threadIdx.x;
    int n0 = blockIdx.x * 16;
    int i = tid >> 4, j = tid & 15;
    float acc = 0.f;
    for (int k0 = 0; k0 < K; k0 += 64) {
        for (int idx = tid; idx < 1024; idx += 256) {
            int r = idx >> 6, cc = idx & 63;
            int gk = k0 + cc, gn = n0 + r;
            As[r][cc] = (gk < K && gn < N_NODES) ? af[(size_t)gn * K + gk] : 0.f;
        }
        for (int idx = tid; idx < 1024; idx += 256) {
            int cc = idx >> 4, jj = idx & 15;
            int gk = k0 + cc;
            float v = 0.f;
            if (gk < K) v = (jj < 8) ? fs[gk * 8 + jj] : fd[gk * 8 + (jj - 8)];
            Fs[cc][jj] = v;
        }
        __syncthreads();
        #pragma unroll 8
        for (int cc = 0; cc < 64; ++cc) acc += As[i][cc] * Fs[cc][j];
        __syncthreads();
    }
    int n = n0 + i;
    if (n < N_NODES) {
        if (j < 8) es[n * 8 + j] = acc;
        else       ed[n * 8 + (j - 8)] = acc;
    }
}

// W [K][NC] fp32 -> Wt [NC][Kp] bf16 (transposed, k-padded)
__global__ __launch_bounds__(256) void k_wtr(const float* __restrict__ W, u16* __restrict__ Wt,
                                             int K, int Kp, int NC) {
    __shared__ float tile[32][33];
    int bx = blockIdx.x, by = blockIdx.y;
    int tid = threadIdx.x;
    for (int idx = tid; idx < 1024; idx += 256) {
        int kr = idx >> 5, nc = idx & 31;
        int gk = by * 32 + kr, gn = bx * 32 + nc;
        tile[kr][nc] = (gk < K) ? W[(size_t)gk * NC + gn] : 0.f;
    }
    __syncthreads();
    for (int idx = tid; idx < 1024; idx += 256) {
        int nr = idx >> 5, kc = idx & 31;
        int gn = bx * 32 + nr, gk = by * 32 + kc;
        Wt[(size_t)gn * Kp + gk] = f2bf(tile[kc][nr]);
    }
}

// ---------------- bf16 MFMA GEMM: Cb[M,NC] (bf16) = A[M,Kp] @ Bt[NC,Kp]^T ----------------
__global__ __launch_bounds__(256) void k_gemm_mfma(const u16* __restrict__ Ab,
                                                   const u16* __restrict__ Bt,
                                                   u16* __restrict__ Cb,
                                                   int M, int Kp, int NC) {
    __shared__ u16 As[128 * 32];
    __shared__ u16 Bs[128 * 32];
    int tid = threadIdx.x;
    int wave = tid >> 6, lane = tid & 63;
    int bm = blockIdx.y * 128, bn = blockIdx.x * 128;
    int wm = (wave >> 1) * 64, wn = (wave & 1) * 64;
    int l16 = lane & 15, q = lane >> 4;
    f32x4 acc[4][4] = {};
    for (int k0 = 0; k0 < Kp; k0 += 32) {
        #pragma unroll
        for (int it = 0; it < 2; ++it) {
            int seg = tid + it * 256;
            int row = seg >> 2, sq = seg & 3;
            uint4 va = {0u, 0u, 0u, 0u};
            int grow = bm + row;
            if (grow < M) va = *(const uint4*)(Ab + (size_t)grow * Kp + k0 + sq * 8);
            *(uint4*)(As + row * 32 + ((sq ^ (row & 3)) * 8)) = va;
            uint4 vb = *(const uint4*)(Bt + (size_t)(bn + row) * Kp + k0 + sq * 8);
            *(uint4*)(Bs + row * 32 + ((sq ^ (row & 3)) * 8)) = vb;
        }
        __syncthreads();
        bf16x8 fa[4], fb[4];
        #pragma unroll
        for (int mi = 0; mi < 4; ++mi) {
            int row = wm + mi * 16 + l16;
            fa[mi] = *(const bf16x8*)(As + row * 32 + ((q ^ (row & 3)) * 8));
            int col = wn + mi * 16 + l16;
            fb[mi] = *(const bf16x8*)(Bs + col * 32 + ((q ^ (col & 3)) * 8));
        }
        #pragma unroll
        for (int mi = 0; mi < 4; ++mi)
            #pragma unroll
            for (int ni = 0; ni < 4; ++ni)
                acc[mi][ni] = __builtin_amdgcn_mfma_f32_16x16x32_bf16(fa[mi], fb[ni], acc[mi][ni], 0, 0, 0);
        __syncthreads();
    }
    #pragma unroll
    for (int mi = 0; mi < 4; ++mi) {
        int row0 = bm + wm + mi * 16 + q * 4;
        #pragma unroll
        for (int ni = 0; ni < 4; ++ni) {
            int col = bn + wn + ni * 16 + l16;
            #pragma unroll
            for (int r = 0; r < 4; ++r) {
                int row = row0 + r;
                if (row < M) Cb[(size_t)row * NC + col] = f2bf(acc[mi][ni][r]);
            }
        }
    }
}

// ---------------- per-node softmax over incoming edges (wave per node, fp32) ----------------
__global__ void k_alpha(const float* __restrict__ es, const float* __restrict__ ed,
                        const int* __restrict__ rowp, const int* __restrict__ ssrc,
                        float* __restrict__ alpha, float* __restrict__ wsum) {
    int wid = (blockIdx.x * blockDim.x + threadIdx.x) >> 6;
    int lane = threadIdx.x & 63;
    if (wid >= N_NODES) return;
    int n = wid;
    int s0 = rowp[n], deg = rowp[n + 1] - s0;
    int h = lane & 7, ei = lane >> 3;
    float edh = ed[n * 8 + h];
    float m = -1e30f;
    for (int b = 0; b < deg; b += 8) {
        int e = b + ei;
        if (e < deg) {
            int src = ssrc[s0 + e];
            float x = es[src * 8 + h] + edh;
            x = x > 0.f ? x : 0.2f * x;
            m = fmaxf(m, x);
        }
    }
    m = fmaxf(m, __shfl_xor(m, 8));
    m = fmaxf(m, __shfl_xor(m, 16));
    m = fmaxf(m, __shfl_xor(m, 32));
    float ssum = 0.f;
    for (int b = 0; b < deg; b += 8) {
        int e = b + ei;
        if (e < deg) {
            int src = ssrc[s0 + e];
            float x = es[src * 8 + h] + edh;
            x = x > 0.f ? x : 0.2f * x;
            ssum += __expf(x - m);
        }
    }
    ssum += __shfl_xor(ssum, 8);
    ssum += __shfl_xor(ssum, 16);
    ssum += __shfl_xor(ssum, 32);
    float inv = 1.f / ssum;
    for (int b = 0; b < deg; b += 8) {
        int e = b + ei;
        if (e < deg) {
            int src = ssrc[s0 + e];
            float x = es[src * 8 + h] + edh;
            x = x > 0.f ? x : 0.2f * x;
            float a = __expf(x - m) * inv;
            alpha[(size_t)(s0 + e) * 8 + h] = a;
            float w = a;
            w += __shfl_xor(w, 1);
            w += __shfl_xor(w, 2);
            w += __shfl_xor(w, 4);
            if (h == 0) wsum[s0 + e] = w;
        }
    }
}

// ---------------- aggregation (bf16 h gather) ----------------
template <int C, int T>
__global__ __launch_bounds__(T) void k_aggregate_b(const u16* __restrict__ h,
                            const float* __restrict__ alpha,
                            const float* __restrict__ wsum, const int* __restrict__ rowp,
                            const int* __restrict__ ssrc, const float* __restrict__ cprev,
                            const float* __restrict__ bias, float* __restrict__ fnext,
                            float* __restrict__ cnext) {
    constexpr int CPT = C / T;   // 2 or 4
    int n = blockIdx.x, t = threadIdx.x;
    int cb = t * CPT;
    int s0 = rowp[n], s1 = rowp[n + 1];
    float acc[CPT] = {};
    float oc0 = 0.f, oc1 = 0.f;
    #pragma unroll 2
    for (int s = s0; s < s1; ++s) {
        int src = ssrc[s];
        const u16* hr = h + (size_t)src * 8 * C + cb;
        float4 a01 = *(const float4*)(alpha + (size_t)s * 8);
        float4 a23 = *(const float4*)(alpha + (size_t)s * 8 + 4);
        float aa[8] = {a01.x, a01.y, a01.z, a01.w, a23.x, a23.y, a23.z, a23.w};
        #pragma unroll
        for (int hh = 0; hh < 8; ++hh) {
            if (CPT == 4) {
                uint2 v = *(const uint2*)(hr + hh * C);
                acc[0] += aa[hh] * bf2f(v.x & 0xffff);
                acc[1] += aa[hh] * bf2f(v.x >> 16);
                acc[2] += aa[hh] * bf2f(v.y & 0xffff);
                acc[3] += aa[hh] * bf2f(v.y >> 16);
            } else {
                unsigned v = *(const unsigned*)(hr + hh * C);
                acc[0] += aa[hh] * bf2f(v & 0xffff);
                acc[1] += aa[hh] * bf2f(v >> 16);
            }
        }
        float w = wsum[s];
        oc0 += w * cprev[src * 2];
        oc1 += w * cprev[src * 2 + 1];
    }
    #pragma unroll
    for (int i = 0; i < CPT; ++i)
        fnext[(size_t)n * C + cb + i] = selu_f(acc[i] * 0.125f + bias[cb + i]);
    if (t == 0) {
        oc0 *= 0.2f * 0.125f;
        oc1 *= 0.2f * 0.125f;
        float a0 = cprev[n * 2], a1 = cprev[n * 2 + 1];
        cnext[n * 2]     = (a0 == 0.f) ? 0.f : ((a0 == 1.f) ? 1.f : oc0);
        cnext[n * 2 + 1] = (a1 == 1.f) ? 1.f : ((a1 == 0.f) ? 0.f : oc1);
    }
}

// ---------------- layer 4: coords only ----------------
__global__ void k_coords4(const float* __restrict__ wsum, const int* __restrict__ rowp,
                          const int* __restrict__ ssrc, const float* __restrict__ cprev,
                          float* __restrict__ outp) {
    int n = blockIdx.x * 256 + threadIdx.x;
    if (n >= N_NODES) return;
    int s0 = rowp[n], s1 = rowp[n + 1];
    float oc0 = 0.f, oc1 = 0.f;
    for (int s = s0; s < s1; ++s) {
        int src = ssrc[s];
        float w = wsum[s];
        oc0 += w * cprev[src * 2];
        oc1 += w * cprev[src * 2 + 1];
    }
    oc0 *= 0.2f * 0.125f;
    oc1 *= 0.2f * 0.125f;
    float a0 = cprev[n * 2], a1 = cprev[n * 2 + 1];
    outp[n * 2]     = (a0 == 0.f) ? 0.f : ((a0 == 1.f) ? 1.f : oc0);
    outp[n * 2 + 1] = (a1 == 1.f) ? 1.f : ((a1 == 0.f) ? 0.f : oc1);
}

extern "C" void kernel_launch(void* const* d_in, const int* in_sizes, int n_in,
                              void* d_out, int out_size, void* d_ws, size_t ws_size,
                              hipStream_t stream) {
    const float* data = (const float*)d_in[0];
    const int* ei = (const int*)d_in[1];
    const float* W0 = (const float*)d_in[2];
    const float* b0 = (const float*)d_in[3];
    int E = in_sizes[1] / 2;           // 40000
    int Esz = E + N_NODES;             // +self loops

    char* wp = (char*)d_ws;
    size_t off = 0;
    auto alloc = [&](size_t bytes) {
        void* p = wp + off;
        off += (bytes + 1023) & ~(size_t)1023;
        return p;
    };
    u16*   hbuf  = (u16*)alloc((size_t)N_NODES * 4096 * 2);
    float* af    = (float*)alloc((size_t)N_NODES * 516 * 4);
    float* fA    = (float*)alloc((size_t)N_NODES * 512 * 4);
    float* fB    = (float*)alloc((size_t)N_NODES * 512 * 4);
    u16*   afb   = (u16*)alloc((size_t)N_NODES * 544 * 2);
    u16*   Wtb   = (u16*)alloc((size_t)4096 * 544 * 2);
    float* alpha = (float*)alloc((size_t)Esz * 8 * 4);
    float* wsum  = (float*)alloc((size_t)Esz * 4);
    float* es    = (float*)alloc((size_t)N_NODES * 8 * 4);
    float* ebd   = (float*)alloc((size_t)N_NODES * 8 * 4);
    float* fs    = (float*)alloc(516 * 8 * 4);
    float* fd    = (float*)alloc(516 * 8 * 4);
    float* c0    = (float*)alloc(N_NODES * 2 * 4);
    float* c1    = (float*)alloc(N_NODES * 2 * 4);
    float* c2    = (float*)alloc(N_NODES * 2 * 4);
    float* c3    = (float*)alloc(N_NODES * 2 * 4);
    int* cnt  = (int*)alloc(N_NODES * 4);
    int* rowp = (int*)alloc((N_NODES + 1) * 4);
    int* cur  = (int*)alloc(N_NODES * 4);
    int* ssrc = (int*)alloc(Esz * 4);

    hipMemsetAsync(cnt, 0, N_NODES * 4, stream);
    hipMemsetAsync(cur, 0, N_NODES * 4, stream);
    int gE = (Esz + 255) / 256;
    k_count<<<gE, 256, 0, stream>>>(ei, cnt, E, Esz);
    k_scan<<<1, 1024, 0, stream>>>(cnt, rowp, N_NODES);
    k_fill<<<gE, 256, 0, stream>>>(ei, rowp, cur, ssrc, E, Esz);
    k_feat0<<<N_NODES, 256, 0, stream>>>(data, W0, b0, fA, c0);

    struct LP { const float *W, *as, *ad, *bs; int K, C; };
    LP L[4] = {
        {(const float*)d_in[4],  (const float*)d_in[5],  (const float*)d_in[6],  (const float*)d_in[7],  258, 512},
        {(const float*)d_in[8],  (const float*)d_in[9],  (const float*)d_in[10], (const float*)d_in[11], 516, 256},
        {(const float*)d_in[12], (const float*)d_in[13], (const float*)d_in[14], (const float*)d_in[15], 262, 128},
        {(const float*)d_in[16], (const float*)d_in[17], (const float*)d_in[18], (const float*)d_in[19], 136, 20},
    };
    float* cbuf[4] = {c0, c1, c2, c3};
    float* featin[4] = {fA, fB, fA, fB};
    int FC[4] = {256, 512, 256, 128};

    for (int li = 0; li < 4; ++li) {
        LP& lp = L[li];
        const float* p[4] = {nullptr, nullptr, nullptr, nullptr};
        for (int j = 0; j <= li; ++j) p[j] = cbuf[li - j];
        int Kp = ((lp.K + 31) / 32) * 32;
        k_assemble<<<N_NODES, 256, 0, stream>>>(af, afb, p[0], p[1], p[2], p[3], li + 1,
                                                featin[li], FC[li], lp.K, Kp);
        k_fold2<<<lp.K, 64, 0, stream>>>(lp.W, lp.as, lp.ad, fs, fd, lp.K, lp.C);
        k_e2<<<(N_NODES + 15) / 16, 256, 0, stream>>>(af, fs, fd, es, ebd, lp.K);
        if (li < 3) {
            int NCc = lp.C * 8;
            k_wtr<<<dim3(NCc / 32, Kp / 32), 256, 0, stream>>>(lp.W, Wtb, lp.K, Kp, NCc);
            k_gemm_mfma<<<dim3(NCc / 128, (N_NODES + 127) / 128), 256, 0, stream>>>(
                afb, Wtb, hbuf, N_NODES, Kp, NCc);
        }
        k_alpha<<<(N_NODES + 3) / 4, 256, 0, stream>>>(es, ebd, rowp, ssrc, alpha, wsum);
        if (li == 0)
            k_aggregate_b<512, 128><<<N_NODES, 128, 0, stream>>>(hbuf, alpha, wsum, rowp, ssrc,
                                                                 cbuf[0], lp.bs, fB, cbuf[1]);
        else if (li == 1)
            k_aggregate_b<256, 64><<<N_NODES, 64, 0, stream>>>(hbuf, alpha, wsum, rowp, ssrc,
                                                               cbuf[1], lp.bs, fA, cbuf[2]);
        else if (li == 2)
            k_aggregate_b<128, 64><<<N_NODES, 64, 0, stream>>>(hbuf, alpha, wsum, rowp, ssrc,
                                                               cbuf[2], lp.bs, fB, cbuf[3]);
        else
            k_coords4<<<(N_NODES + 255) / 256, 256, 0, stream>>>(wsum, rowp, ssrc, cbuf[3],
                                                                 (float*)d_out);
    }
}